// Round 12
// baseline (185.355 us; speedup 1.0000x reference)
//
#include <hip/hip_runtime.h>

// GCN: out[m,n,o] = (A_hat relu(A_hat (x W1) + b1) W_out[m])[n,o] + b_out[m,o]
// A_hat = D^-1/2 (A + I) D^-1/2.
// R12 = R11 with prop1 4-way column-sliced:
//  - g stored slice-major: 4 slices x 32 cols; slice = 3.2MB -> FITS one XCD's
//    4MB L2 (R9 proved slicing kills the 150MB L2-miss traffic; R10's failure
//    was ILP=1 + 8x epilogue, fixed here: 32-edge unroll = 2 uint4 in flight,
//    only 4 slices, row = 64B = one cache line per edge).
//  - slice = blockIdx&3 (XCD round-robin), partial projection to g2part[4][N][8],
//    finalize sums slices (cross-slice combine must precede the ReLU).
//  - prep, gemm core, prop2: R11-identical.

constexpr int CIN = 128;
constexpr int SSHIFT = 8;        // 256 nodes per super-bucket
constexpr int NBLKB = 256;       // partition blocks == scan chunk size
constexpr int CSR_CAP = 10240;   // LDS sort capacity (mean ~8163, std ~90)

typedef __attribute__((ext_vector_type(8))) short short8v;
typedef __attribute__((ext_vector_type(4))) float float4v;

__device__ inline unsigned pack_bf16x2(float a, float b) {
  unsigned ua = __float_as_uint(a), ub = __float_as_uint(b);
  ua = (ua + 0x7FFFu + ((ua >> 16) & 1u)) >> 16;
  ub = (ub + 0x7FFFu + ((ub >> 16) & 1u)) >> 16;
  return ua | (ub << 16);
}
__device__ inline float bf_lo(unsigned u) { return __uint_as_float(u << 16); }
__device__ inline float bf_hi(unsigned u) { return __uint_as_float(u & 0xFFFF0000u); }
__device__ inline void split1(float v, unsigned short& h, unsigned short& lo) {
  unsigned ua = __float_as_uint(v);
  unsigned hb = (ua + 0x7FFFu + ((ua >> 16) & 1u)) >> 16;
  float fh = __uint_as_float(hb << 16);
  float rl = v - fh;
  unsigned ub = __float_as_uint(rl);
  h = (unsigned short)hb;
  lo = (unsigned short)((ub + 0x7FFFu + ((ub >> 16) & 1u)) >> 16);
}

// ---------- pass A: per-block super-bucket histogram ----------
__global__ __launch_bounds__(256) void histsb_k(const int* __restrict__ dst,
    int* __restrict__ blockhist, int E, int nsb) {
  __shared__ int lh[256];
  int b = blockIdx.x, t = threadIdx.x;
  lh[t] = 0;
  __syncthreads();
  int per = (E + gridDim.x - 1) / gridDim.x;
  int s0 = b * per, s1 = min(E, s0 + per);
  for (int i = s0 + t; i < s1; i += 256) atomicAdd(&lh[dst[i] >> SSHIFT], 1);
  __syncthreads();
  if (t < nsb) blockhist[t * NBLKB + b] = lh[t];
}

// exclusive scan over NSC entries, 256/block; writes per-chunk totals
__global__ __launch_bounds__(256) void scan_k(const int* __restrict__ v_in,
    int* __restrict__ excl_out, int* __restrict__ btot, int n) {
  __shared__ int wsum[4];
  int t = threadIdx.x, l = t & 63, w = t >> 6;
  int i = blockIdx.x * 256 + t;
  int v = (i < n) ? v_in[i] : 0;
  int orig = v;
  #pragma unroll
  for (int off = 1; off < 64; off <<= 1) {
    int u = __shfl_up(v, off);
    if (l >= off) v += u;
  }
  if (l == 63) wsum[w] = v;
  __syncthreads();
  int add = 0;
  #pragma unroll
  for (int j = 0; j < 4; ++j) if (j < w) add += wsum[j];
  v += add;
  if (i < n) excl_out[i] = v - orig;
  if (t == 255) btot[blockIdx.x] = v;
}

// ---------- pass B: write edges to exact (block,super) ranges ----------
__global__ __launch_bounds__(256) void stageB_k(const int* __restrict__ src,
    const int* __restrict__ dst, const int* __restrict__ soff,
    const int* __restrict__ btot, unsigned* __restrict__ stage, int E, int nsb) {
  __shared__ int loff[256];
  __shared__ int wsum[4];
  int b = blockIdx.x, t = threadIdx.x, l = t & 63, w = t >> 6;
  int bv = (t < nsb) ? btot[t] : 0;
  int vv = bv;
  #pragma unroll
  for (int o = 1; o < 64; o <<= 1) { int u = __shfl_up(vv, o); if (l >= o) vv += u; }
  if (l == 63) wsum[w] = vv;
  __syncthreads();
  int add = 0;
  #pragma unroll
  for (int j = 0; j < 4; ++j) if (j < w) add += wsum[j];
  int bexcl = vv + add - bv;           // exclusive prefix of btot at t
  if (t < nsb) loff[t] = soff[t * NBLKB + b] + bexcl;
  __syncthreads();
  int per = (E + gridDim.x - 1) / gridDim.x;
  int s0 = b * per, s1 = min(E, s0 + per);
  for (int i = s0 + t; i < s1; i += 256) {
    int d = dst[i], s = src[i];
    int pos = atomicAdd(&loff[d >> SSHIFT], 1);
    stage[pos] = (unsigned)s | ((unsigned)(d & 255) << 17);  // src<2^17, dloc 8b
  }
}

// ---------- per-super LDS count-sort: stage -> per-node CSR + dinv ----------
__global__ __launch_bounds__(256) void csrsb_k(const unsigned* __restrict__ stage,
    const int* __restrict__ btot, int* __restrict__ row_ptr, int* __restrict__ csr,
    float* __restrict__ dinv, int N, int E, int nsb) {
  __shared__ int cnt[256], off[256], cur[256], sboff[256];
  __shared__ unsigned ebuf[CSR_CAP];
  __shared__ int sbuf[CSR_CAP];
  __shared__ int wsum[4];
  int k = blockIdx.x, t = threadIdx.x, l = t & 63, w = t >> 6;
  cnt[t] = 0; cur[t] = 0;
  // inline top-level scan of btot
  {
    int bv = (t < nsb) ? btot[t] : 0;
    int vv = bv;
    #pragma unroll
    for (int o = 1; o < 64; o <<= 1) { int u = __shfl_up(vv, o); if (l >= o) vv += u; }
    if (l == 63) wsum[w] = vv;
    __syncthreads();
    int add = 0;
    #pragma unroll
    for (int j = 0; j < 4; ++j) if (j < w) add += wsum[j];
    sboff[t] = vv + add - bv;
  }
  __syncthreads();
  int r0 = sboff[k];
  int r1 = (k + 1 < nsb) ? sboff[k + 1] : E;
  int len = r1 - r0;
  bool fits = len <= CSR_CAP;
  if (fits) {
    for (int i = t; i < len; i += 256) {
      unsigned s = stage[r0 + i];
      ebuf[i] = s;
      atomicAdd(&cnt[s >> 17], 1);
    }
  } else {
    for (int i = r0 + t; i < r1; i += 256) atomicAdd(&cnt[stage[i] >> 17], 1);
  }
  __syncthreads();
  {  // 256-entry exclusive scan (4 waves)
    int v = cnt[t], orig = v;
    #pragma unroll
    for (int o = 1; o < 64; o <<= 1) {
      int u = __shfl_up(v, o);
      if (l >= o) v += u;
    }
    if (l == 63) wsum[w] = v;
    __syncthreads();
    int add = 0;
    #pragma unroll
    for (int j = 0; j < 4; ++j) if (j < w) add += wsum[j];
    int excl = v + add - orig;
    off[t] = excl;
    int n = (k << SSHIFT) + t;
    if (n < N) {
      row_ptr[n] = r0 + excl;
      dinv[n] = rsqrtf((float)(orig + 1));
    }
    if (k == nsb - 1 && t == 255) row_ptr[N] = E;
  }
  __syncthreads();
  if (fits) {
    for (int i = t; i < len; i += 256) {
      unsigned s = ebuf[i];
      int dl = s >> 17;
      int pos = off[dl] + atomicAdd(&cur[dl], 1);
      sbuf[pos] = (int)(s & 0x1FFFF);
    }
    __syncthreads();
    for (int i = t; i < len; i += 256) csr[r0 + i] = sbuf[i];
  } else {
    for (int i = r0 + t; i < r1; i += 256) {
      unsigned s = stage[i];
      int dl = s >> 17;
      int pos = r0 + off[dl] + atomicAdd(&cur[dl], 1);
      csr[pos] = (int)(s & 0x1FFFF);
    }
  }
}

// ---------- g(bf16, 4-slice-major) = dinv[n]*(x@W1), MFMA split-bf16 ----------
__global__ __launch_bounds__(256) void gemm_k(const float* __restrict__ x,
    const float* __restrict__ W, const float* __restrict__ dinv,
    unsigned* __restrict__ gu, int nrows) {
  __shared__ unsigned short Bh[16384];   // W hi  [kstep][coltile][lane][j]
  __shared__ unsigned short Bl[16384];   // W lo
  __shared__ unsigned short Ah[4096];    // x hi  [kg][row][j]  (one k-step)
  __shared__ unsigned short Al[4096];    // x lo
  int t = threadIdx.x, l = t & 63, w = t >> 6;
  for (int idx = t; idx < 16384; idx += 256) {
    int k = idx >> 7, col = idx & 127;
    unsigned short hb, lb;
    split1(W[idx], hb, lb);
    int addr = (((k >> 5) * 8 + (col >> 4)) * 64 +
                (((k >> 3) & 3) * 16 + (col & 15))) * 8 + (k & 7);
    Bh[addr] = hb;
    Bl[addr] = lb;
  }

  int row0 = blockIdx.x * 128;
  int ct0 = w * 2;                       // wave's two col-tiles
  float4v acc[8][2];
  #pragma unroll
  for (int i = 0; i < 8; ++i) { acc[i][0] = (float4v)0.f; acc[i][1] = (float4v)0.f; }
  int arow = l & 15;
  int kg = l >> 4;
  int srow = t >> 1, skh = t & 1;        // staging: thread -> (row, k-half)
  int sgrow = min(row0 + srow, nrows - 1);

  for (int ks = 0; ks < 4; ++ks) {
    __syncthreads();
    {                                    // split this k-step's x-tile
      const float* xp = &x[(size_t)sgrow * CIN + ks * 32 + skh * 16];
      float f[16];
      *(float4*)&f[0]  = *(const float4*)xp;
      *(float4*)&f[4]  = *(const float4*)(xp + 4);
      *(float4*)&f[8]  = *(const float4*)(xp + 8);
      *(float4*)&f[12] = *(const float4*)(xp + 12);
      #pragma unroll
      for (int h = 0; h < 2; ++h) {
        short8v ah_, al_;
        #pragma unroll
        for (int j = 0; j < 8; ++j) {
          unsigned short hb, lb;
          split1(f[h * 8 + j], hb, lb);
          ah_[j] = (short)hb;
          al_[j] = (short)lb;
        }
        int g = skh * 2 + h;
        *(short8v*)&Ah[(g * 128 + srow) * 8] = ah_;
        *(short8v*)&Al[(g * 128 + srow) * 8] = al_;
      }
    }
    __syncthreads();
    short8v bh0 = *(short8v*)&Bh[((ks * 8 + ct0) * 64 + l) * 8];
    short8v bh1 = *(short8v*)&Bh[((ks * 8 + ct0 + 1) * 64 + l) * 8];
    short8v bl0 = *(short8v*)&Bl[((ks * 8 + ct0) * 64 + l) * 8];
    short8v bl1 = *(short8v*)&Bl[((ks * 8 + ct0 + 1) * 64 + l) * 8];
    #pragma unroll
    for (int rt = 0; rt < 8; ++rt) {
      int ar = arow + rt * 16;
      short8v ah = *(short8v*)&Ah[(kg * 128 + ar) * 8];
      short8v al = *(short8v*)&Al[(kg * 128 + ar) * 8];
      acc[rt][0] = __builtin_amdgcn_mfma_f32_16x16x32_bf16(ah, bh0, acc[rt][0], 0, 0, 0);
      acc[rt][1] = __builtin_amdgcn_mfma_f32_16x16x32_bf16(ah, bh1, acc[rt][1], 0, 0, 0);
      acc[rt][0] = __builtin_amdgcn_mfma_f32_16x16x32_bf16(ah, bl0, acc[rt][0], 0, 0, 0);
      acc[rt][1] = __builtin_amdgcn_mfma_f32_16x16x32_bf16(ah, bl1, acc[rt][1], 0, 0, 0);
      acc[rt][0] = __builtin_amdgcn_mfma_f32_16x16x32_bf16(al, bh0, acc[rt][0], 0, 0, 0);
      acc[rt][1] = __builtin_amdgcn_mfma_f32_16x16x32_bf16(al, bh1, acc[rt][1], 0, 0, 0);
    }
  }
  // epilogue: D col = l&15, row = 4*(l>>4)+reg [HW-verified]
  // slice = coltile>>1 (32 cols); within slice uint idx = (ct&1)*8 + (l&15)>>1
  #pragma unroll
  for (int rt = 0; rt < 8; ++rt) {
    #pragma unroll
    for (int r = 0; r < 4; ++r) {
      int row = row0 + rt * 16 + (l >> 4) * 4 + r;
      bool ok = row < nrows;
      float dv = ok ? dinv[row] : 0.f;
      #pragma unroll
      for (int c = 0; c < 2; ++c) {
        float val = acc[rt][c][r] * dv;
        float other = __shfl_xor(val, 1);
        int ct = ct0 + c;
        int slice = ct >> 1;
        if (ok && !(l & 1))
          gu[((size_t)slice * nrows + row) * 16 + (ct & 1) * 8 + ((l & 15) >> 1)] =
              pack_bf16x2(val, other);
      }
    }
  }
}

// ---------- propagate-1: 4-slice XCD-L2-resident gather + partial projection ----------
#define ACC8(U) do { \
  acc[0] += bf_lo((U).x); acc[1] += bf_hi((U).x); \
  acc[2] += bf_lo((U).y); acc[3] += bf_hi((U).y); \
  acc[4] += bf_lo((U).z); acc[5] += bf_hi((U).z); \
  acc[6] += bf_lo((U).w); acc[7] += bf_hi((U).w); } while (0)

__global__ __launch_bounds__(256) void prop1s4_k(const uint4* __restrict__ g4,
    const int* __restrict__ row_ptr, const int* __restrict__ csr,
    const float* __restrict__ dinv, const float* __restrict__ b1,
    const float* __restrict__ Wout, float* __restrict__ g2part,
    int N, int waves_per_slice) {
  int slice = blockIdx.x & 3;          // XCD round-robin: XCD k serves slice k&3
  int chunk = blockIdx.x >> 2;
  int t = threadIdx.x, l = t & 63, w = t >> 6;
  int q = l & 3, sub = l >> 2;         // 16 edge-groups x 4 lanes (64B row = 1 line)
  int j = sub & 7;                     // output column (2 copies: sub, sub+8)
  float bb[8], wj[8];
  #pragma unroll
  for (int c = 0; c < 8; ++c) {
    int col = slice * 32 + 8 * q + c;
    bb[c] = b1[col];
    wj[c] = Wout[(j >> 1) * 256 + col * 2 + (j & 1)];
  }
  const uint4* gb = g4 + (size_t)slice * N * 4 + q;
  float* gp = g2part + (size_t)slice * N * 8;

  for (int n = chunk * 4 + w; n < N; n += waves_per_slice) {
    int start = row_ptr[n], end = row_ptr[n + 1];
    float d = dinv[n];
    float acc[8];
    #pragma unroll
    for (int c = 0; c < 8; ++c) acc[c] = 0.f;
    for (int base = start; base < end; base += 64) {
      int cnt = min(64, end - base);
      int eb = (base + l < end) ? csr[base + l] : 0;
      int i = 0;
      for (; i + 32 <= cnt; i += 32) {      // 2 uint4 loads in flight
        int s0 = __shfl(eb, i + sub);
        int s1 = __shfl(eb, i + 16 + sub);
        uint4 u0 = gb[(size_t)s0 * 4];
        uint4 u1 = gb[(size_t)s1 * 4];
        ACC8(u0); ACC8(u1);
      }
      for (; i + 16 <= cnt; i += 16) {
        int s0 = __shfl(eb, i + sub);
        uint4 u0 = gb[(size_t)s0 * 4];
        ACC8(u0);
      }
      if (i < cnt) {
        int idx = i + sub;
        bool vld = idx < cnt;
        int s0 = __shfl(eb, vld ? idx : i);
        uint4 u0 = gb[(size_t)s0 * 4];
        if (vld) { ACC8(u0); }
      }
    }
    // merge the 16 edge-groups (xor over sub bits; q preserved)
    #pragma unroll
    for (int c = 0; c < 8; ++c) {
      acc[c] += __shfl_xor(acc[c], 4);
      acc[c] += __shfl_xor(acc[c], 8);
      acc[c] += __shfl_xor(acc[c], 16);
      acc[c] += __shfl_xor(acc[c], 32);
    }
    // self-loop exactly once (after merge; uniform across subs)
    uint4 us = gb[(size_t)n * 4];
    ACC8(us);
    // relu + partial projection over this slice's 32 cols
    float p = 0.f;
    #pragma unroll
    for (int c = 0; c < 8; ++c) {
      float y = fmaxf(fmaf(acc[c], d, bb[c]), 0.f);
      p = fmaf(y, wj[c], p);
    }
    p += __shfl_xor(p, 1);               // reduce over q (4 lanes)
    p += __shfl_xor(p, 2);
    if (l < 32 && (l & 3) == 0) gp[(size_t)n * 8 + j] = p;   // lanes 0,4,..,28: j=0..7
  }
}

// ---------- finalize: sum 4 slice partials, apply dinv, pack bf16 ----------
__global__ __launch_bounds__(256) void finalize_k(const float* __restrict__ g2part,
    const float* __restrict__ dinv, unsigned* __restrict__ g2w, int N) {
  int tid = blockIdx.x * 256 + threadIdx.x;
  if (tid >= N * 4) return;
  int n = tid >> 2, jp = tid & 3;
  float s0 = 0.f, s1 = 0.f;
  #pragma unroll
  for (int s = 0; s < 4; ++s) {
    const float* p = &g2part[((size_t)s * N + n) * 8 + jp * 2];
    s0 += p[0]; s1 += p[1];
  }
  float d = dinv[n];
  g2w[n * 4 + jp] = pack_bf16x2(d * s0, d * s1);
}

// ---------- propagate-2: 2 threads/node, uint2 bf16x4 per edge ----------
__global__ __launch_bounds__(256) void prop2_k(const uint2* __restrict__ g2v,
    const int* __restrict__ row_ptr, const int* __restrict__ csr,
    const float* __restrict__ dinv, const float* __restrict__ bout,
    float* __restrict__ out, int N) {
  int tid = blockIdx.x * 256 + threadIdx.x;
  int n = tid >> 1, hf = tid & 1;
  if (n >= N) return;
  uint2 us = g2v[n * 2 + hf];      // self-loop
  float a0 = bf_lo(us.x), a1 = bf_hi(us.x);
  float a2 = bf_lo(us.y), a3 = bf_hi(us.y);
  int e = row_ptr[n], e1 = row_ptr[n + 1];
  for (; e + 4 <= e1; e += 4) {
    int i0 = csr[e], i1 = csr[e + 1], i2 = csr[e + 2], i3 = csr[e + 3];
    uint2 u0 = g2v[i0 * 2 + hf], u1 = g2v[i1 * 2 + hf];
    uint2 u2 = g2v[i2 * 2 + hf], u3 = g2v[i3 * 2 + hf];
    a0 += (bf_lo(u0.x) + bf_lo(u1.x)) + (bf_lo(u2.x) + bf_lo(u3.x));
    a1 += (bf_hi(u0.x) + bf_hi(u1.x)) + (bf_hi(u2.x) + bf_hi(u3.x));
    a2 += (bf_lo(u0.y) + bf_lo(u1.y)) + (bf_lo(u2.y) + bf_lo(u3.y));
    a3 += (bf_hi(u0.y) + bf_hi(u1.y)) + (bf_hi(u2.y) + bf_hi(u3.y));
  }
  for (; e < e1; ++e) {
    uint2 u = g2v[csr[e] * 2 + hf];
    a0 += bf_lo(u.x); a1 += bf_hi(u.x);
    a2 += bf_lo(u.y); a3 += bf_hi(u.y);
  }
  float d = dinv[n];
  float2 o0 = make_float2(fmaf(d, a0, bout[hf * 4 + 0]), fmaf(d, a1, bout[hf * 4 + 1]));
  float2 o1 = make_float2(fmaf(d, a2, bout[hf * 4 + 2]), fmaf(d, a3, bout[hf * 4 + 3]));
  *(float2*)&out[(size_t)(hf * 2 + 0) * (2 * N) + 2 * n] = o0;
  *(float2*)&out[(size_t)(hf * 2 + 1) * (2 * N) + 2 * n] = o1;
}

extern "C" void kernel_launch(void* const* d_in, const int* in_sizes, int n_in,
                              void* d_out, int out_size, void* d_ws, size_t ws_size,
                              hipStream_t stream) {
  const float* x    = (const float*)d_in[0];
  const int*   ei   = (const int*)d_in[1];
  const float* W1   = (const float*)d_in[2];
  const float* b1   = (const float*)d_in[3];
  const float* Wout = (const float*)d_in[4];
  const float* bout = (const float*)d_in[5];
  float* out = (float*)d_out;

  const int N = in_sizes[0] / CIN;       // 50000
  const int E = in_sizes[1] / 2;         // 1600000
  const int* srcp = ei;
  const int* dstp = ei + E;
  const int NSB = (N + 255) >> SSHIFT;   // 196 super-buckets
  const int NSC = NSB * NBLKB;           // 50176 scan entries

  char* ws = (char*)d_ws;
  size_t off = 0;
  auto alloc = [&](size_t bytes) -> void* {
    void* p = ws + off;
    off = (off + bytes + 511) & ~(size_t)511;
    return p;
  };
  unsigned*       gu        = (unsigned*)alloc((size_t)N * 64 * 4);      // bf16 g, 4-slice-major
  float*          g2part    = (float*)alloc((size_t)4 * N * 8 * 4);      // fp32 partials
  unsigned short* g2u       = (unsigned short*)alloc((size_t)N * 8 * 2); // bf16 g2
  float*          dinv      = (float*)alloc((size_t)N * 4);
  int*            blockhist = (int*)alloc((size_t)NSC * 4);
  int*            soff      = (int*)alloc((size_t)NSC * 4);
  int*            btot      = (int*)alloc(256 * 4);
  int*            row_ptr   = (int*)alloc((size_t)(N + 1) * 4);
  int*            csr       = (int*)alloc((size_t)E * 4);
  unsigned*       stage     = (unsigned*)alloc((size_t)E * 4);
  (void)ws_size; (void)n_in; (void)out_size;

  histsb_k<<<NBLKB, 256, 0, stream>>>(dstp, blockhist, E, NSB);
  scan_k<<<NSB, 256, 0, stream>>>(blockhist, soff, btot, NSC);
  stageB_k<<<NBLKB, 256, 0, stream>>>(srcp, dstp, soff, btot, stage, E, NSB);
  csrsb_k<<<NSB, 256, 0, stream>>>(stage, btot, row_ptr, csr, dinv, N, E, NSB);

  gemm_k<<<(N + 127) / 128, 256, 0, stream>>>(x, W1, dinv, gu, N);

  const int P1_BLOCKS = 2048;            // 512 chunks x 4 slices; 2048 waves/slice
  prop1s4_k<<<P1_BLOCKS, 256, 0, stream>>>((const uint4*)gu, row_ptr, csr, dinv, b1,
                                           Wout, g2part, N, (P1_BLOCKS / 4) * 4);
  finalize_k<<<(N * 4 + 255) / 256, 256, 0, stream>>>(g2part, dinv, (unsigned*)g2u, N);
  prop2_k<<<(2 * N + 255) / 256, 256, 0, stream>>>((const uint2*)g2u, row_ptr, csr,
                                                   dinv, bout, out, N);
}